// Round 3
// baseline (870.961 us; speedup 1.0000x reference)
//
#include <hip/hip_runtime.h>
#include <math.h>

// Problem constants
#define KK     128
#define HH     384
#define H3     1152
#define PP     200
#define LL     50
#define VV     512
#define BB     256
#define II     16
#define NSTEPS 3

#define VP     513     // vals LDS pitch (epilogue only)
#define KP     129     // keys LDS pitch
#define NT     576     // 9 waves; 2*NT == H3

#define GH_G   (HH/4)              // 96 k-groups for w_hh
#define GI_G   (PP/4)              // 50 k-groups for w_ih
#define WU_HH  (GH_G * NT * 4)     // 221184 uints (884 KB)
#define WU_IH  (GI_G * NT * 4)     // 115200 uints (460 KB)

__device__ __forceinline__ unsigned f2bf(float f) {
    unsigned u = __float_as_uint(f);
    unsigned r = u + 0x7FFFu + ((u >> 16) & 1u);   // RNE
    return (r >> 16) & 0xFFFFu;
}
__device__ __forceinline__ float bflo(unsigned u) { return __uint_as_float(u << 16); }
__device__ __forceinline__ float bfhi(unsigned u) { return __uint_as_float(u & 0xFFFF0000u); }
__device__ __forceinline__ float rcpf(float x) { return __builtin_amdgcn_rcpf(x); }
__device__ __forceinline__ float sigm(float x) { return rcpf(1.f + __expf(-x)); }
__device__ __forceinline__ float tanh_fast(float x) {
    float xc = fminf(fmaxf(x, -15.f), 15.f);
    float t = __expf(2.f * xc);
    return 1.f - 2.f * rcpf(t + 1.f);
}

// Pack weights: uint4-friendly layout.
// wT_hh[(g*NT + t)*4 + m] = pack(w_hh[2t][4g+m], w_hh[2t+1][4g+m]),  g<96
// wT_ih[(g*NT + t)*4 + m] = pack(w_ih[2t][4g+m], w_ih[2t+1][4g+m]),  g<50
__global__ void pack_weights(const float* __restrict__ w_hh,
                             const float* __restrict__ w_ih,
                             unsigned* __restrict__ ws)
{
    int idx = blockIdx.x * 256 + threadIdx.x;
    if (idx < WU_HH) {
        int g = idx / (NT * 4);
        int r = idx - g * (NT * 4);
        int t = r >> 2, m = r & 3;
        int k = 4 * g + m, j0 = 2 * t;
        unsigned lo = f2bf(w_hh[(long)j0 * HH + k]);
        unsigned hi = f2bf(w_hh[(long)(j0 + 1) * HH + k]);
        ws[idx] = (hi << 16) | lo;
    } else if (idx < WU_HH + WU_IH) {
        int q = idx - WU_HH;
        int g = q / (NT * 4);
        int r = q - g * (NT * 4);
        int t = r >> 2, m = r & 3;
        int k = 4 * g + m, j0 = 2 * t;
        unsigned lo = f2bf(w_ih[(long)j0 * PP + k]);
        unsigned hi = f2bf(w_ih[(long)(j0 + 1) * PP + k]);
        ws[idx] = (hi << 16) | lo;
    }
}

struct Smem {
    float vals[LL * VP];   // epilogue staging only
    float keys[LL * KP];
    float h[HH];           // 16B-aligned (offset 32100 floats)
    float gi[H3];
    float gh[H3];
    float prog[PP];        // 16B-aligned (offset 34788 floats)
    float ra[LL];
    float wmm[LL];
    float rl[LL];
    float wl[LL];
    float rowoff[LL];
};

__global__ __launch_bounds__(NT, 1)
void symop_main(const int* __restrict__ instr,
                const float* __restrict__ gate_emb,
                const float* __restrict__ program_emb,
                const float* __restrict__ primitive_emb,
                const uint4* __restrict__ wT_hh,
                const uint4* __restrict__ wT_ih,
                const float* __restrict__ b_ih,
                const float* __restrict__ b_hh,
                const float* __restrict__ keys_g,
                const float* __restrict__ init_value,
                float* __restrict__ out)
{
    __shared__ Smem sm;

    const int tid  = threadIdx.x;
    const int lane = tid & 63;
    const int wid  = tid >> 6;
    const int b    = blockIdx.x;

    // init
    for (int idx = tid; idx < LL * KK; idx += NT) {
        int l = idx >> 7, k = idx & 127;
        sm.keys[l * KP + k] = keys_g[idx];
    }
    for (int j = tid; j < HH; j += NT) sm.h[j] = keys_g[j & 127];

    float vreg[LL];                     // vals column tid (tid < 512)
    if (tid < VV) {
        const float iv = init_value[tid];
        #pragma unroll
        for (int l = 0; l < LL; ++l) vreg[l] = iv;
    }
    __syncthreads();

    const int j0 = 2 * tid;
    const float2 bh2 = *(const float2*)(b_hh + j0);
    const float2 bi2 = *(const float2*)(b_ih + j0);

    for (int i = 0; i < II; ++i) {
        const int word = instr[i * BB + b];
        const float ge0 = gate_emb[2 * word], ge1 = gate_emb[2 * word + 1];
        const float gmx = fmaxf(ge0, ge1);
        const float e0 = __expf(ge0 - gmx), e1 = __expf(ge1 - gmx);
        const float g0 = e0 * rcpf(e0 + e1), g1 = 1.0f - g0;
        const float primv = (tid < VV) ? primitive_emb[(long)word * VV + tid] : 0.f;
        const float* pge = program_emb + (long)word * PP;

        for (int k = tid; k < PP; k += NT) sm.prog[k] = pge[k];
        __syncthreads();

        // gi = W_ih @ prog + b_ih  (uint4-packed bf16, thread owns j0,j0+1)
        {
            float a0 = 0.f, a1 = 0.f;
            const uint4* wp = wT_ih + tid;
            #pragma unroll 5
            for (int g = 0; g < GI_G; ++g) {
                uint4  w4 = wp[g * NT];
                float4 p4 = *(const float4*)(sm.prog + 4 * g);
                a0 = fmaf(bflo(w4.x), p4.x, a0); a1 = fmaf(bfhi(w4.x), p4.x, a1);
                a0 = fmaf(bflo(w4.y), p4.y, a0); a1 = fmaf(bfhi(w4.y), p4.y, a1);
                a0 = fmaf(bflo(w4.z), p4.z, a0); a1 = fmaf(bfhi(w4.z), p4.z, a1);
                a0 = fmaf(bflo(w4.w), p4.w, a0); a1 = fmaf(bfhi(w4.w), p4.w, a1);
            }
            sm.gi[j0]     = a0 + bi2.x;
            sm.gi[j0 + 1] = a1 + bi2.y;
        }
        // gi consumed only after later barriers

        for (int t = 0; t < NSTEPS; ++t) {
            // attention logits: 100 dots of len 128; 4 lanes per dot
            if (tid < 4 * 2 * LL) {
                const int dot = tid >> 2;
                const int sub = tid & 3;
                const int l   = (dot < LL) ? dot : dot - LL;
                const float* p  = (dot < LL) ? (sm.h + KK) : (sm.h + 2 * KK);
                const float* kr = sm.keys + l * KP;
                float acc = 0.f;
                #pragma unroll
                for (int kk = 0; kk < KK / 4; ++kk) {
                    int k = sub + 4 * kk;
                    acc = fmaf(p[k], kr[k], acc);
                }
                acc += __shfl_xor(acc, 1, 64);
                acc += __shfl_xor(acc, 2, 64);
                if (sub == 0) {
                    if (dot < LL) sm.rl[l] = acc; else sm.wl[l] = acc;
                }
            }
            __syncthreads();

            // wave-level softmax over 50: wave0 -> read attn, wave1 -> write mask
            if (wid < 2) {
                const float* src = (wid == 0) ? sm.rl : sm.wl;
                float v = (lane < LL) ? src[lane] : -1e30f;
                float m = v;
                #pragma unroll
                for (int mm = 32; mm >= 1; mm >>= 1) m = fmaxf(m, __shfl_xor(m, mm, 64));
                float e = (lane < LL) ? __expf(v - m) : 0.f;
                float s = e;
                #pragma unroll
                for (int mm = 32; mm >= 1; mm >>= 1) s += __shfl_xor(s, mm, 64);
                if (lane < LL) {
                    float r = e * rcpf(s);
                    if (wid == 0) sm.ra[lane] = r;
                    else          sm.wmm[lane] = r;
                }
            }
            __syncthreads();

            // read_value + vals update — pure register FMAs
            if (tid < VV) {
                float rv = 0.f;
                #pragma unroll
                for (int l = 0; l < LL; ++l) rv = fmaf(sm.ra[l], vreg[l], rv);
                const float nv = g0 * primv + g1 * rv;
                #pragma unroll
                for (int l = 0; l < LL; ++l)
                    vreg[l] = fmaf(sm.wmm[l], nv - vreg[l], vreg[l]);
            }

            // gh = W_hh @ h + b_hh (uint4-packed; reads sm.h — no barrier needed)
            {
                float a0 = 0.f, a1 = 0.f;
                const uint4* wp = wT_hh + tid;
                #pragma unroll 8
                for (int g = 0; g < GH_G; ++g) {
                    uint4  w4 = wp[g * NT];
                    float4 h4 = *(const float4*)(sm.h + 4 * g);
                    a0 = fmaf(bflo(w4.x), h4.x, a0); a1 = fmaf(bfhi(w4.x), h4.x, a1);
                    a0 = fmaf(bflo(w4.y), h4.y, a0); a1 = fmaf(bfhi(w4.y), h4.y, a1);
                    a0 = fmaf(bflo(w4.z), h4.z, a0); a1 = fmaf(bfhi(w4.z), h4.z, a1);
                    a0 = fmaf(bflo(w4.w), h4.w, a0); a1 = fmaf(bfhi(w4.w), h4.w, a1);
                }
                sm.gh[j0]     = a0 + bh2.x;
                sm.gh[j0 + 1] = a1 + bh2.y;
            }
            __syncthreads();

            // GRU pointwise
            if (tid < HH) {
                const int j = tid;
                const float r = sigm(sm.gi[j] + sm.gh[j]);
                const float z = sigm(sm.gi[HH + j] + sm.gh[HH + j]);
                const float n = tanh_fast(sm.gi[2 * HH + j] + r * sm.gh[2 * HH + j]);
                sm.h[j] = (1.f - z) * n + z * sm.h[j];
            }
            __syncthreads();
        }
    }

    // dump vals registers to LDS for the epilogue
    if (tid < VV) {
        #pragma unroll
        for (int l = 0; l < LL; ++l) sm.vals[l * VP + tid] = vreg[l];
    }
    __syncthreads();

    // log-softmax row offsets
    for (int l = wid; l < LL; l += NT / 64) {
        const float* row = sm.vals + l * VP;
        float m = -1e30f;
        for (int v = lane; v < VV; v += 64) m = fmaxf(m, row[v]);
        #pragma unroll
        for (int mm = 32; mm >= 1; mm >>= 1) m = fmaxf(m, __shfl_xor(m, mm, 64));
        float s = 0.f;
        for (int v = lane; v < VV; v += 64) s += __expf(row[v] - m);
        #pragma unroll
        for (int mm = 32; mm >= 1; mm >>= 1) s += __shfl_xor(s, mm, 64);
        if (lane == 0) sm.rowoff[l] = m + logf(s);
    }
    __syncthreads();

    // actions[b, v, l] = vals[l, v] - rowoff[l]; lanes over l (coalesced)
    {
        const int vs = wid;
        const int l  = lane;
        if (l < LL) {
            const float off = sm.rowoff[l];
            float* ob = out + (long)b * VV * LL + l;
            for (int v = vs; v < VV; v += NT / 64) {
                ob[(long)v * LL] = sm.vals[l * VP + v] - off;
            }
        }
    }
}

__global__ void ta_copy(const int* __restrict__ ta, float* __restrict__ out2)
{
    int idx = blockIdx.x * 256 + threadIdx.x;
    if (idx < BB * LL) {
        int b2 = idx / LL, l = idx % LL;
        out2[idx] = (float)ta[l * BB + b2];
    }
}

extern "C" void kernel_launch(void* const* d_in, const int* in_sizes, int n_in,
                              void* d_out, int out_size, void* d_ws, size_t ws_size,
                              hipStream_t stream)
{
    const int*   instr        = (const int*)  d_in[0];
    const int*   true_actions = (const int*)  d_in[1];
    const float* gate_emb     = (const float*)d_in[2];
    const float* program_emb  = (const float*)d_in[3];
    const float* primitive_emb= (const float*)d_in[4];
    const float* w_ih         = (const float*)d_in[5];
    const float* w_hh         = (const float*)d_in[6];
    const float* b_ih         = (const float*)d_in[7];
    const float* b_hh         = (const float*)d_in[8];
    const float* scratch_keys = (const float*)d_in[9];
    const float* init_value   = (const float*)d_in[10];

    unsigned* wt = (unsigned*)d_ws;                 // 1.35 MB
    const uint4* wT_hh = (const uint4*)wt;
    const uint4* wT_ih = (const uint4*)(wt + WU_HH);

    {
        int total = WU_HH + WU_IH;
        pack_weights<<<(total + 255) / 256, 256, 0, stream>>>(w_hh, w_ih, wt);
    }

    float* out = (float*)d_out;
    float* out_actions = out;
    float* out_ta      = out + (long)BB * VV * LL;

    symop_main<<<BB, NT, 0, stream>>>(instr, gate_emb, program_emb, primitive_emb,
                                      wT_hh, wT_ih, b_ih, b_hh,
                                      scratch_keys, init_value, out_actions);

    ta_copy<<<(BB * LL + 255) / 256, 256, 0, stream>>>(true_actions, out_ta);
}

// Round 4
// 527.398 us; speedup vs baseline: 1.6514x; 1.6514x over previous
//
#include <hip/hip_runtime.h>
#include <math.h>

// Problem constants
#define KK     128
#define HH     384
#define H3     1152
#define PP     200
#define LL     50
#define VV     512
#define BB     256
#define II     16
#define NSTEPS 3

#define KP     129    // keys LDS pitch (f32)
#define NT     576    // 9 waves; 2*NT == H3

#define GH_O   (HH/8)            // 48 k-octets for w_hh
#define GI_O   (PP/8)            // 25 k-octets for w_ih
#define WH_U   (GH_O * NT * 8)   // 221184 uints (884 KB)
#define WI_U   (GI_O * NT * 8)   // 115200 uints (460 KB)

typedef _Float16 half2v __attribute__((ext_vector_type(2)));
union uhcvt { unsigned u; half2v h; };

__device__ __forceinline__ float dot2(unsigned a, unsigned b, float c) {
    uhcvt x, y; x.u = a; y.u = b;
    return __builtin_amdgcn_fdot2(x.h, y.h, c, false);
}
__device__ __forceinline__ unsigned packh2(float a, float b) {
    uhcvt u; u.h.x = (_Float16)a; u.h.y = (_Float16)b; return u.u;
}
__device__ __forceinline__ float rcpf(float x) { return __builtin_amdgcn_rcpf(x); }
__device__ __forceinline__ float sigm(float x) { return rcpf(1.f + __expf(-x)); }
__device__ __forceinline__ float tanh_fast(float x) {
    float xc = fminf(fmaxf(x, -15.f), 15.f);
    float t = __expf(2.f * xc);
    return 1.f - 2.f * rcpf(t + 1.f);
}

// Weight pack (f16 half2 along k):
// layout uint index: ((g*NT + t)*2 + s)*4 + m  ->  j = 2t+s, k = 8g+2m (+1 in .y)
__global__ void pack_weights(const float* __restrict__ w_hh,
                             const float* __restrict__ w_ih,
                             unsigned* __restrict__ ws)
{
    int idx = blockIdx.x * 256 + threadIdx.x;
    if (idx < WH_U) {
        int g = idx / (NT * 8);
        int r = idx - g * (NT * 8);
        int t = r >> 3, s = (r >> 2) & 1, m = r & 3;
        int j = 2 * t + s, k = 8 * g + 2 * m;
        ws[idx] = packh2(w_hh[(long)j * HH + k], w_hh[(long)j * HH + k + 1]);
    } else if (idx < WH_U + WI_U) {
        int q = idx - WH_U;
        int g = q / (NT * 8);
        int r = q - g * (NT * 8);
        int t = r >> 3, s = (r >> 2) & 1, m = r & 3;
        int j = 2 * t + s, k = 8 * g + 2 * m;
        ws[idx] = packh2(w_ih[(long)j * PP + k], w_ih[(long)j * PP + k + 1]);
    }
}

struct Smem {
    unsigned hpk[HH / 2];     // 192 uints, 16B-aligned (offset 0)
    unsigned progpk[104];     // 100 used, padded so next is 16B-aligned
    float h[HH];              // f32 h (logits)
    float keys[LL * KP];
    float gi[H3];
    float gh[H3];
    float ra[LL], wmm[LL], rl[LL], wl[LL], rowoff[LL];
    float partial[8 * LL];
};  // ~41 KB

__global__ __attribute__((amdgpu_waves_per_eu(3, 3))) __launch_bounds__(NT)
void symop_main(const int* __restrict__ instr,
                const float* __restrict__ gate_emb,
                const float* __restrict__ program_emb,
                const float* __restrict__ primitive_emb,
                const uint4* __restrict__ wT_hh,
                const uint4* __restrict__ wT_ih,
                const float* __restrict__ b_ih,
                const float* __restrict__ b_hh,
                const float* __restrict__ keys_g,
                const float* __restrict__ init_value,
                float* __restrict__ out)
{
    __shared__ Smem sm;

    const int tid  = threadIdx.x;
    const int lane = tid & 63;
    const int wid  = tid >> 6;
    const int b    = blockIdx.x;

    // init
    for (int idx = tid; idx < LL * KK; idx += NT) {
        int l = idx >> 7, k = idx & 127;
        sm.keys[l * KP + k] = keys_g[idx];
    }
    float hcur = 0.f;
    if (tid < HH) {
        hcur = keys_g[tid & 127];
        sm.h[tid] = hcur;
    }
    if (tid < HH / 2)
        sm.hpk[tid] = packh2(keys_g[(2 * tid) & 127], keys_g[(2 * tid + 1) & 127]);

    float vreg[LL];
    if (tid < VV) {
        const float iv = init_value[tid];
        #pragma unroll
        for (int l = 0; l < LL; ++l) vreg[l] = iv;
    }
    __syncthreads();

    const int j0 = 2 * tid;
    const float2 bh2 = *(const float2*)(b_hh + j0);
    const float2 bi2 = *(const float2*)(b_ih + j0);

    for (int i = 0; i < II; ++i) {
        const int word = instr[i * BB + b];
        const float ge0 = gate_emb[2 * word], ge1 = gate_emb[2 * word + 1];
        const float gmx = fmaxf(ge0, ge1);
        const float e0 = __expf(ge0 - gmx), e1 = __expf(ge1 - gmx);
        const float g0 = e0 * rcpf(e0 + e1), g1 = 1.0f - g0;
        const float primv = (tid < VV) ? primitive_emb[(long)word * VV + tid] : 0.f;
        const float* pge = program_emb + (long)word * PP;

        if (tid < PP / 2) {
            float2 pg = *(const float2*)(pge + 2 * tid);
            sm.progpk[tid] = packh2(pg.x, pg.y);
        }
        __syncthreads();

        // gi = W_ih @ prog + b_ih  (dot2, thread owns j0,j0+1)
        {
            float a0 = bi2.x, a1 = bi2.y;
            const uint4* wp = wT_ih + (size_t)tid * 2;
            #pragma unroll 5
            for (int g = 0; g < GI_O; ++g) {
                uint4 wa = wp[(size_t)g * (NT * 2)];
                uint4 wb = wp[(size_t)g * (NT * 2) + 1];
                uint4 hp = *(const uint4*)(sm.progpk + 4 * g);
                a0 = dot2(wa.x, hp.x, a0); a0 = dot2(wa.y, hp.y, a0);
                a0 = dot2(wa.z, hp.z, a0); a0 = dot2(wa.w, hp.w, a0);
                a1 = dot2(wb.x, hp.x, a1); a1 = dot2(wb.y, hp.y, a1);
                a1 = dot2(wb.z, hp.z, a1); a1 = dot2(wb.w, hp.w, a1);
            }
            sm.gi[j0] = a0; sm.gi[j0 + 1] = a1;
        }
        // gi consumed only after later barriers

        for (int t = 0; t < NSTEPS; ++t) {
            // attention logits: 100 dots of len 128; 4 lanes per dot (f32)
            if (tid < 4 * 2 * LL) {
                const int dot = tid >> 2;
                const int sub = tid & 3;
                const int l   = (dot < LL) ? dot : dot - LL;
                const float* p  = (dot < LL) ? (sm.h + KK) : (sm.h + 2 * KK);
                const float* kr = sm.keys + l * KP;
                float acc = 0.f;
                #pragma unroll
                for (int kk = 0; kk < KK / 4; ++kk) {
                    int k = sub + 4 * kk;
                    acc = fmaf(p[k], kr[k], acc);
                }
                acc += __shfl_xor(acc, 1, 64);
                acc += __shfl_xor(acc, 2, 64);
                if (sub == 0) {
                    if (dot < LL) sm.rl[l] = acc; else sm.wl[l] = acc;
                }
            }
            __syncthreads();

            // wave-level softmax over 50
            if (wid < 2) {
                const float* src = (wid == 0) ? sm.rl : sm.wl;
                float v = (lane < LL) ? src[lane] : -1e30f;
                float m = v;
                #pragma unroll
                for (int mm = 32; mm >= 1; mm >>= 1) m = fmaxf(m, __shfl_xor(m, mm, 64));
                float e = (lane < LL) ? __expf(v - m) : 0.f;
                float s = e;
                #pragma unroll
                for (int mm = 32; mm >= 1; mm >>= 1) s += __shfl_xor(s, mm, 64);
                if (lane < LL) {
                    float r = e * rcpf(s);
                    if (wid == 0) sm.ra[lane] = r;
                    else          sm.wmm[lane] = r;
                }
            }
            __syncthreads();

            // read_value + vals update — pure register FMAs
            if (tid < VV) {
                float rv = 0.f;
                #pragma unroll
                for (int l = 0; l < LL; ++l) rv = fmaf(sm.ra[l], vreg[l], rv);
                const float nv = g0 * primv + g1 * rv;
                #pragma unroll
                for (int l = 0; l < LL; ++l)
                    vreg[l] = fmaf(sm.wmm[l], nv - vreg[l], vreg[l]);
            }

            // gh = W_hh @ h + b_hh (dot2 on packed f16 h; reads hpk — barrier-safe)
            {
                float a0 = bh2.x, a1 = bh2.y;
                const uint4* wp = wT_hh + (size_t)tid * 2;
                #pragma unroll 4
                for (int g = 0; g < GH_O; ++g) {
                    uint4 wa = wp[(size_t)g * (NT * 2)];
                    uint4 wb = wp[(size_t)g * (NT * 2) + 1];
                    uint4 hp = *(const uint4*)(sm.hpk + 4 * g);
                    a0 = dot2(wa.x, hp.x, a0); a0 = dot2(wa.y, hp.y, a0);
                    a0 = dot2(wa.z, hp.z, a0); a0 = dot2(wa.w, hp.w, a0);
                    a1 = dot2(wb.x, hp.x, a1); a1 = dot2(wb.y, hp.y, a1);
                    a1 = dot2(wb.z, hp.z, a1); a1 = dot2(wb.w, hp.w, a1);
                }
                sm.gh[j0] = a0; sm.gh[j0 + 1] = a1;
            }
            __syncthreads();

            // GRU pointwise; update register h, f32 LDS h, packed f16 h
            if (tid < HH) {
                const int j = tid;
                const float r = sigm(sm.gi[j] + sm.gh[j]);
                const float z = sigm(sm.gi[HH + j] + sm.gh[HH + j]);
                const float n = tanh_fast(sm.gi[2 * HH + j] + r * sm.gh[2 * HH + j]);
                const float hn = (1.f - z) * n + z * hcur;
                hcur = hn;
                sm.h[j] = hn;
                const float hnb = __shfl_down(hn, 1, 64);
                if (!(tid & 1)) sm.hpk[tid >> 1] = packh2(hn, hnb);
            }
            __syncthreads();
        }
    }

    // epilogue: log-sum-exp per row (values bounded by ~1 -> no max pass needed)
    if (tid < VV) {
        #pragma unroll
        for (int l = 0; l < LL; ++l) {
            float e = __expf(vreg[l]);
            #pragma unroll
            for (int mm = 32; mm >= 1; mm >>= 1) e += __shfl_xor(e, mm, 64);
            if (lane == 0) sm.partial[wid * LL + l] = e;
        }
    }
    __syncthreads();
    if (tid < LL) {
        float s = 0.f;
        #pragma unroll
        for (int w = 0; w < 8; ++w) s += sm.partial[w * LL + tid];
        sm.rowoff[tid] = logf(s);
    }
    __syncthreads();

    // out[b, v, l] = vreg[l] - rowoff[l]; thread v writes 50 contiguous floats
    if (tid < VV) {
        float* ob = out + (long)b * VV * LL + (long)tid * LL;
        #pragma unroll
        for (int l = 0; l < LL; l += 2) {
            float2 w2;
            w2.x = vreg[l]     - sm.rowoff[l];
            w2.y = vreg[l + 1] - sm.rowoff[l + 1];
            *(float2*)(ob + l) = w2;
        }
    }
}

__global__ void ta_copy(const int* __restrict__ ta, float* __restrict__ out2)
{
    int idx = blockIdx.x * 256 + threadIdx.x;
    if (idx < BB * LL) {
        int b2 = idx / LL, l = idx % LL;
        out2[idx] = (float)ta[l * BB + b2];
    }
}

extern "C" void kernel_launch(void* const* d_in, const int* in_sizes, int n_in,
                              void* d_out, int out_size, void* d_ws, size_t ws_size,
                              hipStream_t stream)
{
    const int*   instr        = (const int*)  d_in[0];
    const int*   true_actions = (const int*)  d_in[1];
    const float* gate_emb     = (const float*)d_in[2];
    const float* program_emb  = (const float*)d_in[3];
    const float* primitive_emb= (const float*)d_in[4];
    const float* w_ih         = (const float*)d_in[5];
    const float* w_hh         = (const float*)d_in[6];
    const float* b_ih         = (const float*)d_in[7];
    const float* b_hh         = (const float*)d_in[8];
    const float* scratch_keys = (const float*)d_in[9];
    const float* init_value   = (const float*)d_in[10];

    unsigned* wt = (unsigned*)d_ws;                 // 1.35 MB of ws
    const uint4* wT_hh = (const uint4*)wt;
    const uint4* wT_ih = (const uint4*)(wt + WH_U);

    {
        int total = WH_U + WI_U;
        pack_weights<<<(total + 255) / 256, 256, 0, stream>>>(w_hh, w_ih, wt);
    }

    float* out = (float*)d_out;
    float* out_actions = out;
    float* out_ta      = out + (long)BB * VV * LL;

    symop_main<<<BB, NT, 0, stream>>>(instr, gate_emb, program_emb, primitive_emb,
                                      wT_hh, wT_ih, b_ih, b_hh,
                                      scratch_keys, init_value, out_actions);

    ta_copy<<<(BB * LL + 255) / 256, 256, 0, stream>>>(true_actions, out_ta);
}